// Round 6
// baseline (368.255 us; speedup 1.0000x reference)
//
#include <hip/hip_runtime.h>
#include <hip/hip_bf16.h>

constexpr int BATCH = 4;
constexpr int SEQ   = 2048;
constexpr int DIM   = 768;
constexpr int NH    = 12;
constexpr int HDIM  = 64;

typedef __attribute__((ext_vector_type(8))) short bf16x8;
typedef __attribute__((ext_vector_type(4))) float f32x4;
typedef __attribute__((ext_vector_type(4))) short s16x4;

__device__ inline short f2bf(float f) {
    union { float f; unsigned u; } v; v.f = f;
    unsigned r = (v.u + 0x7fff + ((v.u >> 16) & 1)) >> 16;  // RNE
    return (short)r;
}

__device__ inline unsigned pack_bf16x2(float a, float b) {
    union { __hip_bfloat162 h; unsigned u; } c;
    c.h = __float22bfloat162_rn(make_float2(a, b));
    return c.u;
}

__device__ inline float fast_exp2(float x) {
#if __has_builtin(__builtin_amdgcn_exp2f)
    return __builtin_amdgcn_exp2f(x);
#else
    return __expf(x * 0.6931471805599453f);
#endif
}

__device__ inline void gld16(const short* g, short* l) {
    __builtin_amdgcn_global_load_lds(
        (const __attribute__((address_space(1))) void*)g,
        (__attribute__((address_space(3))) void*)l, 16, 0, 0);
}

__device__ inline bool ctx_at(const void* p, bool isU8, int idx) {
    return isU8 ? (((const unsigned char*)p)[idx] != 0)
                : (((const int*)p)[idx] != 0);
}

// ---------------------------------------------------------------------------
// prep: fused fp32->bf16 casts (x, Wq, Wk, Wv, Wo) + mask-layout detect.
// ---------------------------------------------------------------------------
__global__ __launch_bounds__(256) void prep_kernel(
    const float* __restrict__ x,  const float* __restrict__ Wq,
    const float* __restrict__ Wk, const float* __restrict__ Wv,
    const float* __restrict__ Wo,
    short* __restrict__ xb,  short* __restrict__ Wqb,
    short* __restrict__ Wkb, short* __restrict__ Wvb,
    short* __restrict__ Wob,
    const unsigned char* __restrict__ ctxm, int ctxbytes, int* __restrict__ flag) {
    const int blk = blockIdx.x;
    constexpr int XBLK = (BATCH * SEQ * DIM / 4) / 256;  // 6144
    constexpr int WBLK = (DIM * DIM / 4) / 256;          // 576

    if (blk == XBLK + 4 * WBLK) {
        __shared__ int cnt;
        if (threadIdx.x == 0) cnt = 0;
        __syncthreads();
        int local = 0;
        for (int i = threadIdx.x; i < ctxbytes; i += 256)
            if ((i & 3) != 0 && ctxm[i] != 0) local++;
        atomicAdd(&cnt, local);
        __syncthreads();
        if (threadIdx.x == 0) *flag = (cnt > 0) ? 1 : 0;
        return;
    }

    const float* src; short* dst; int i;
    if (blk < XBLK) {
        src = x; dst = xb;
        i = blk * 256 + threadIdx.x;
    } else {
        const int r = blk - XBLK;
        const int w = r / WBLK;
        src = (w == 0) ? Wq : (w == 1) ? Wk : (w == 2) ? Wv : Wo;
        dst = (w == 0) ? Wqb : (w == 1) ? Wkb : (w == 2) ? Wvb : Wob;
        i = (r - w * WBLK) * 256 + threadIdx.x;
    }
    float4 v = ((const float4*)src)[i];
    s16x4 o;
    o.x = f2bf(v.x); o.y = f2bf(v.y); o.z = f2bf(v.z); o.w = f2bf(v.w);
    ((s16x4*)dst)[i] = o;
}

// ---------------------------------------------------------------------------
// m97-style MFMA GEMM (unchanged).
// ---------------------------------------------------------------------------
template <bool BF16OUT>
__global__ __launch_bounds__(256) void gemm_mfma(
    const short* __restrict__ A,
    const short* __restrict__ W0, const float* __restrict__ bias0, void* __restrict__ C0,
    const short* __restrict__ W1, const float* __restrict__ bias1, void* __restrict__ C1,
    const short* __restrict__ W2, const float* __restrict__ bias2, void* __restrict__ C2,
    float scale0) {
    constexpr int N  = DIM;
    constexpr int Kd = DIM;

    const short* W; const float* bias; void* C; float scale;
    if (blockIdx.z == 0)      { W = W0; bias = bias0; C = C0; scale = scale0; }
    else if (blockIdx.z == 1) { W = W1; bias = bias1; C = C1; scale = 1.f; }
    else                      { W = W2; bias = bias2; C = C2; scale = 1.f; }

    const int tid  = threadIdx.x;
    const int wave = tid >> 6;
    const int lane = tid & 63;
    const int quad = lane >> 4;
    const int l16  = lane & 15;
    const int wm   = wave & 1;
    const int wn   = wave >> 1;
    const int m0   = blockIdx.y * 128;
    const int n0   = blockIdx.x * 128;

    __shared__ short As[128 * 32];
    __shared__ short Bs[128 * 32];

    const int srow = tid >> 2;
    const int skq  = tid & 3;
    const short* Ag = A + (size_t)(m0 + srow) * Kd + skq * 8;
    const short* Wg = W + (size_t)(n0 + srow) * Kd + skq * 8;
    short* AsP = As + srow * 32 + skq * 8;
    short* BsP = Bs + srow * 32 + skq * 8;

    f32x4 acc[4][4] = {};

    for (int kt = 0; kt < Kd; kt += 32) {
        __syncthreads();
        gld16(Ag + kt,                AsP);
        gld16(Ag + kt + 64 * Kd,      AsP + 64 * 32);
        gld16(Wg + kt,                BsP);
        gld16(Wg + kt + 64 * Kd,      BsP + 64 * 32);
        __syncthreads();

        bf16x8 af[4], bfr[4];
#pragma unroll
        for (int mt = 0; mt < 4; ++mt)
            af[mt] = *(const bf16x8*)&As[(wm * 64 + mt * 16 + l16) * 32 + quad * 8];
#pragma unroll
        for (int nt = 0; nt < 4; ++nt)
            bfr[nt] = *(const bf16x8*)&Bs[(wn * 64 + nt * 16 + l16) * 32 + quad * 8];
#pragma unroll
        for (int mt = 0; mt < 4; ++mt)
#pragma unroll
            for (int nt = 0; nt < 4; ++nt)
                acc[mt][nt] = __builtin_amdgcn_mfma_f32_16x16x32_bf16(
                    af[mt], bfr[nt], acc[mt][nt], 0, 0, 0);
    }

    float bv[4];
#pragma unroll
    for (int nt = 0; nt < 4; ++nt) bv[nt] = bias[n0 + wn * 64 + nt * 16 + l16];

#pragma unroll
    for (int mt = 0; mt < 4; ++mt)
#pragma unroll
        for (int nt = 0; nt < 4; ++nt)
#pragma unroll
            for (int reg = 0; reg < 4; ++reg) {
                const int m = m0 + wm * 64 + mt * 16 + quad * 4 + reg;
                const int n = n0 + wn * 64 + nt * 16 + l16;
                const float v = (acc[mt][nt][reg] + bv[nt]) * scale;
                if (BF16OUT) ((short*)C)[(size_t)m * N + n] = f2bf(v);
                else         ((float*)C)[(size_t)m * N + n] = v;
            }
}

// ---------------------------------------------------------------------------
// V pre-transpose (one pass): V[b,s,h*64+d] -> Vtg[((b*NH+h)*64+d)*SEQ + tile*64 + s']
// where within each 64-key tile, s' = 4*kl + g for key = g*16+kl (the
// s-permutation that makes attention's packed-P writes line up with V).
// Reads are scattered 8B (one pass only); writes fully coalesced.
// ---------------------------------------------------------------------------
__global__ __launch_bounds__(256) void vtrans_kernel(
    const short* __restrict__ Vb, short* __restrict__ Vtg) {
    const int b  = blockIdx.z;
    const int h  = blockIdx.y;
    const int k0 = blockIdx.x * 64;
    const int kl = threadIdx.x & 15;
    const int d0 = (threadIdx.x >> 4) * 4;   // 0..60

    s16x4 vr[4];
#pragma unroll
    for (int g = 0; g < 4; ++g)
        vr[g] = *(const s16x4*)(Vb + (size_t)(b * SEQ + k0 + g * 16 + kl) * DIM
                                + h * HDIM + d0);
#pragma unroll
    for (int i = 0; i < 4; ++i) {
        s16x4 w = {vr[0][i], vr[1][i], vr[2][i], vr[3][i]};
        *(s16x4*)(Vtg + (size_t)((b * NH + h) * HDIM + d0 + i) * SEQ + k0 + 4 * kl) = w;
    }
}

// ---------------------------------------------------------------------------
// MFMA flash attention v4 = r4 structure + reg-prefetch double-buffer +
// mask-after-pack + l-via-ones-MFMA + pre-transposed V.
// Block = (b, h, 128 q rows); 4 waves x 32 q rows (2 row groups).
// No-max exp2 softmax (0.125*log2e folded into Q at the QKV GEMM).
// ---------------------------------------------------------------------------
__global__ __launch_bounds__(256) void attn_mfma4(
    const short* __restrict__ Qb, const short* __restrict__ Kb,
    const short* __restrict__ Vtg, const void* __restrict__ ctxp,
    const int* __restrict__ flagp, short* __restrict__ Ob) {
    const int b    = blockIdx.z;
    const int h    = blockIdx.y;
    const int q0   = blockIdx.x * 128;
    const int tid  = threadIdx.x;
    const int wave = tid >> 6;
    const int lane = tid & 63;
    const int quad = lane >> 4;
    const int l16  = lane & 15;
    const bool isU8 = (*flagp != 0);

    __shared__ short Ks[64][72];       // [key][d]
    __shared__ short Vt[64][72];       // [d][s]  (s-permuted keys)
    __shared__ short Ps[4][32][72];    // per-wave P, [q row][s]

    // Q fragments: rows q0 + wave*32 + rg*16 + l16.
    bf16x8 qf[2][2];
#pragma unroll
    for (int rg = 0; rg < 2; ++rg) {
        const short* qp = Qb + (size_t)(b * SEQ + q0 + wave * 32 + rg * 16 + l16) * DIM
                        + h * HDIM + quad * 8;
        qf[rg][0] = *(const bf16x8*)qp;
        qf[rg][1] = *(const bf16x8*)(qp + 32);
    }

    // ~qctx per (rg, C-row): 0 for context rows, ~0 for target rows.
    unsigned nmb[2][4];
#pragma unroll
    for (int rg = 0; rg < 2; ++rg)
#pragma unroll
        for (int reg = 0; reg < 4; ++reg)
            nmb[rg][reg] = ctx_at(ctxp, isU8,
                b * SEQ + q0 + wave * 32 + rg * 16 + quad * 4 + reg) ? 0u : 0xFFFFFFFFu;

    bf16x8 ones;
#pragma unroll
    for (int i = 0; i < 8; ++i) ones[i] = (short)0x3F80;  // bf16 1.0

    f32x4 accl[2] = {};
    f32x4 acc[2][4] = {};

    // Staging maps (per thread): K: key=tid>>2, d-part (tid&3)*16;
    // V: d=tid>>2, s-part (tid&3)*16. Both 2x uint4, fully coalesced.
    const int srow = tid >> 2;
    const int spart = (tid & 3) * 16;
    const short* Kg0 = Kb + (size_t)(b * SEQ + srow) * DIM + h * HDIM + spart;
    const short* Vg0 = Vtg + (size_t)((b * NH + h) * HDIM + srow) * SEQ + spart;

    // Prefetch tile 0.
    uint4 kr[2], vr[2];
    bool cpre;
    {
        const uint4* kp = (const uint4*)Kg0;
        kr[0] = kp[0]; kr[1] = kp[1];
        const uint4* vp = (const uint4*)Vg0;
        vr[0] = vp[0]; vr[1] = vp[1];
        cpre = ctx_at(ctxp, isU8, b * SEQ + lane);
    }

    for (int t = 0; t < SEQ / 64; ++t) {
        __syncthreads();   // prior tile's LDS reads complete
        // Commit prefetched tile to LDS.
        *(uint4*)&Ks[srow][spart]     = kr[0];
        *(uint4*)&Ks[srow][spart + 8] = kr[1];
        *(uint4*)&Vt[srow][spart]     = vr[0];
        *(uint4*)&Vt[srow][spart + 8] = vr[1];

        // Key-keep masks for this tile (from prefetched ctx).
        const unsigned long long kmask = __ballot(cpre);
        unsigned km2[2];
#pragma unroll
        for (int gp = 0; gp < 2; ++gp) {
            const unsigned lo = (unsigned)((kmask >> (gp * 32 + l16)) & 1ull);
            const unsigned hi = (unsigned)((kmask >> (gp * 32 + 16 + l16)) & 1ull);
            km2[gp] = (lo ? 0x0000FFFFu : 0u) | (hi ? 0xFFFF0000u : 0u);
        }
        __syncthreads();

        // Issue next tile's global loads (consumed at next iteration's commit).
        if (t + 1 < SEQ / 64) {
            const int kn = (t + 1) * 64;
            const uint4* kp = (const uint4*)(Kg0 + (size_t)kn * DIM);
            kr[0] = kp[0]; kr[1] = kp[1];
            const uint4* vp = (const uint4*)(Vg0 + kn);
            vr[0] = vp[0]; vr[1] = vp[1];
            cpre = ctx_at(ctxp, isU8, b * SEQ + kn + lane);
        }

        // S = Q @ K^T (log2 domain).
        f32x4 s4[2][4] = {};
#pragma unroll
        for (int ks = 0; ks < 2; ++ks) {
            bf16x8 kf[4];
#pragma unroll
            for (int g = 0; g < 4; ++g)
                kf[g] = *(const bf16x8*)&Ks[g * 16 + l16][ks * 32 + quad * 8];
#pragma unroll
            for (int g = 0; g < 4; ++g) {
                s4[0][g] = __builtin_amdgcn_mfma_f32_16x16x32_bf16(qf[0][ks], kf[g], s4[0][g], 0, 0, 0);
                s4[1][g] = __builtin_amdgcn_mfma_f32_16x16x32_bf16(qf[1][ks], kf[g], s4[1][g], 0, 0, 0);
            }
        }

        // p = exp2(s); pack bf16 pairs; mask by AND; write P (s-order).
#pragma unroll
        for (int rg = 0; rg < 2; ++rg)
#pragma unroll
            for (int reg = 0; reg < 4; ++reg) {
                const float p0 = fast_exp2(s4[rg][0][reg]);
                const float p1 = fast_exp2(s4[rg][1][reg]);
                const float p2 = fast_exp2(s4[rg][2][reg]);
                const float p3 = fast_exp2(s4[rg][3][reg]);
                uint2 w;
                w.x = pack_bf16x2(p0, p1) & (nmb[rg][reg] | km2[0]);
                w.y = pack_bf16x2(p2, p3) & (nmb[rg][reg] | km2[1]);
                *(uint2*)&Ps[wave][rg * 16 + quad * 4 + reg][4 * l16] = w;
            }

        // O += P @ V ; l += P @ 1.
#pragma unroll
        for (int ks = 0; ks < 2; ++ks) {
            bf16x8 pf0 = *(const bf16x8*)&Ps[wave][l16][ks * 32 + quad * 8];
            bf16x8 pf1 = *(const bf16x8*)&Ps[wave][16 + l16][ks * 32 + quad * 8];
            accl[0] = __builtin_amdgcn_mfma_f32_16x16x32_bf16(pf0, ones, accl[0], 0, 0, 0);
            accl[1] = __builtin_amdgcn_mfma_f32_16x16x32_bf16(pf1, ones, accl[1], 0, 0, 0);
#pragma unroll
            for (int dt = 0; dt < 4; ++dt) {
                bf16x8 vf = *(const bf16x8*)&Vt[dt * 16 + l16][ks * 32 + quad * 8];
                acc[0][dt] = __builtin_amdgcn_mfma_f32_16x16x32_bf16(pf0, vf, acc[0][dt], 0, 0, 0);
                acc[1][dt] = __builtin_amdgcn_mfma_f32_16x16x32_bf16(pf1, vf, acc[1][dt], 0, 0, 0);
            }
        }
    }

    float inv[2][4];
#pragma unroll
    for (int rg = 0; rg < 2; ++rg)
#pragma unroll
        for (int reg = 0; reg < 4; ++reg)
            inv[rg][reg] = 1.f / accl[rg][reg];

#pragma unroll
    for (int rg = 0; rg < 2; ++rg)
#pragma unroll
        for (int dt = 0; dt < 4; ++dt)
#pragma unroll
            for (int reg = 0; reg < 4; ++reg) {
                const int q = q0 + wave * 32 + rg * 16 + quad * 4 + reg;
                Ob[(size_t)(b * SEQ + q) * DIM + h * HDIM + dt * 16 + l16] =
                    f2bf(acc[rg][dt][reg] * inv[rg][reg]);
            }
}

// ---------------------------------------------------------------------------
// kernel_launch
// ---------------------------------------------------------------------------
extern "C" void kernel_launch(void* const* d_in, const int* in_sizes, int n_in,
                              void* d_out, int out_size, void* d_ws, size_t ws_size,
                              hipStream_t stream) {
    const float* x   = (const float*)d_in[0];
    const void*  ctx = d_in[1];
    const float* Wq  = (const float*)d_in[2];
    const float* bq  = (const float*)d_in[3];
    const float* Wk  = (const float*)d_in[4];
    const float* bk  = (const float*)d_in[5];
    const float* Wv  = (const float*)d_in[6];
    const float* bv  = (const float*)d_in[7];
    const float* Wo  = (const float*)d_in[8];
    const float* bo  = (const float*)d_in[9];
    float* out = (float*)d_out;

    char* ws = (char*)d_ws;
    int* flag = (int*)ws;
    const size_t bufbf = (size_t)BATCH * SEQ * DIM * sizeof(short);  // 12.6 MB
    const size_t wbuf  = (size_t)DIM * DIM * sizeof(short);          // 1.18 MB
    short* xb  = (short*)(ws + 256);
    short* Qb  = (short*)(ws + 256 + bufbf);
    short* Kb  = (short*)(ws + 256 + 2 * bufbf);
    short* Vb  = (short*)(ws + 256 + 3 * bufbf);
    short* Ab  = (short*)(ws + 256 + 4 * bufbf);
    short* Vtg = (short*)(ws + 256 + 5 * bufbf);
    short* Wqb = (short*)(ws + 256 + 6 * bufbf);
    short* Wkb = (short*)(ws + 256 + 6 * bufbf + wbuf);
    short* Wvb = (short*)(ws + 256 + 6 * bufbf + 2 * wbuf);
    short* Wob = (short*)(ws + 256 + 6 * bufbf + 3 * wbuf);

    constexpr int XBLK = (BATCH * SEQ * DIM / 4) / 256;  // 6144
    constexpr int WBLK = (DIM * DIM / 4) / 256;          // 576
    prep_kernel<<<XBLK + 4 * WBLK + 1, 256, 0, stream>>>(
        x, Wq, Wk, Wv, Wo, xb, Wqb, Wkb, Wvb, Wob,
        (const unsigned char*)ctx, BATCH * SEQ, flag);

    // Q scale = 0.125 * log2(e): scores arrive in exp2 domain.
    dim3 gQKV(DIM / 128, (BATCH * SEQ) / 128, 3);
    gemm_mfma<true><<<gQKV, 256, 0, stream>>>(
        xb, Wqb, bq, Qb, Wkb, bk, Kb, Wvb, bv, Vb, 0.125f * 1.4426950408889634f);

    dim3 gVt(SEQ / 64, NH, BATCH);
    vtrans_kernel<<<gVt, 256, 0, stream>>>(Vb, Vtg);

    dim3 gAttn(SEQ / 128, NH, BATCH);
    attn_mfma4<<<gAttn, 256, 0, stream>>>(Qb, Kb, Vtg, ctx, flag, Ab);

    dim3 gOut(DIM / 128, (BATCH * SEQ) / 128, 1);
    gemm_mfma<false><<<gOut, 256, 0, stream>>>(
        Ab, Wob, bo, out, Wob, bo, out, Wob, bo, out, 1.f);
}

// Round 7
// 357.857 us; speedup vs baseline: 1.0291x; 1.0291x over previous
//
#include <hip/hip_runtime.h>
#include <hip/hip_bf16.h>

constexpr int BATCH = 4;
constexpr int SEQ   = 2048;
constexpr int DIM   = 768;
constexpr int NH    = 12;
constexpr int HDIM  = 64;

typedef __attribute__((ext_vector_type(8))) short bf16x8;
typedef __attribute__((ext_vector_type(4))) float f32x4;
typedef __attribute__((ext_vector_type(4))) short s16x4;

__device__ inline short f2bf(float f) {
    union { float f; unsigned u; } v; v.f = f;
    unsigned r = (v.u + 0x7fff + ((v.u >> 16) & 1)) >> 16;  // RNE
    return (short)r;
}

__device__ inline unsigned pack_bf16x2(float a, float b) {
    union { __hip_bfloat162 h; unsigned u; } c;
    c.h = __float22bfloat162_rn(make_float2(a, b));
    return c.u;
}

__device__ inline float fast_exp2(float x) {
#if __has_builtin(__builtin_amdgcn_exp2f)
    return __builtin_amdgcn_exp2f(x);
#else
    return __expf(x * 0.6931471805599453f);
#endif
}

__device__ inline void gld16(const short* g, short* l) {
    __builtin_amdgcn_global_load_lds(
        (const __attribute__((address_space(1))) void*)g,
        (__attribute__((address_space(3))) void*)l, 16, 0, 0);
}

__device__ inline bool ctx_at(const void* p, bool isU8, int idx) {
    return isU8 ? (((const unsigned char*)p)[idx] != 0)
                : (((const int*)p)[idx] != 0);
}

// ---------------------------------------------------------------------------
// prep: fused fp32->bf16 casts (x, Wq, Wk, Wv, Wo) + mask-layout detect.
// ---------------------------------------------------------------------------
__global__ __launch_bounds__(256) void prep_kernel(
    const float* __restrict__ x,  const float* __restrict__ Wq,
    const float* __restrict__ Wk, const float* __restrict__ Wv,
    const float* __restrict__ Wo,
    short* __restrict__ xb,  short* __restrict__ Wqb,
    short* __restrict__ Wkb, short* __restrict__ Wvb,
    short* __restrict__ Wob,
    const unsigned char* __restrict__ ctxm, int ctxbytes, int* __restrict__ flag) {
    const int blk = blockIdx.x;
    constexpr int XBLK = (BATCH * SEQ * DIM / 4) / 256;  // 6144
    constexpr int WBLK = (DIM * DIM / 4) / 256;          // 576

    if (blk == XBLK + 4 * WBLK) {
        __shared__ int cnt;
        if (threadIdx.x == 0) cnt = 0;
        __syncthreads();
        int local = 0;
        for (int i = threadIdx.x; i < ctxbytes; i += 256)
            if ((i & 3) != 0 && ctxm[i] != 0) local++;
        atomicAdd(&cnt, local);
        __syncthreads();
        if (threadIdx.x == 0) *flag = (cnt > 0) ? 1 : 0;
        return;
    }

    const float* src; short* dst; int i;
    if (blk < XBLK) {
        src = x; dst = xb;
        i = blk * 256 + threadIdx.x;
    } else {
        const int r = blk - XBLK;
        const int w = r / WBLK;
        src = (w == 0) ? Wq : (w == 1) ? Wk : (w == 2) ? Wv : Wo;
        dst = (w == 0) ? Wqb : (w == 1) ? Wkb : (w == 2) ? Wvb : Wob;
        i = (r - w * WBLK) * 256 + threadIdx.x;
    }
    float4 v = ((const float4*)src)[i];
    s16x4 o;
    o.x = f2bf(v.x); o.y = f2bf(v.y); o.z = f2bf(v.z); o.w = f2bf(v.w);
    ((s16x4*)dst)[i] = o;
}

// ---------------------------------------------------------------------------
// m97-style MFMA GEMM (unchanged).
// ---------------------------------------------------------------------------
template <bool BF16OUT>
__global__ __launch_bounds__(256) void gemm_mfma(
    const short* __restrict__ A,
    const short* __restrict__ W0, const float* __restrict__ bias0, void* __restrict__ C0,
    const short* __restrict__ W1, const float* __restrict__ bias1, void* __restrict__ C1,
    const short* __restrict__ W2, const float* __restrict__ bias2, void* __restrict__ C2,
    float scale0) {
    constexpr int N  = DIM;
    constexpr int Kd = DIM;

    const short* W; const float* bias; void* C; float scale;
    if (blockIdx.z == 0)      { W = W0; bias = bias0; C = C0; scale = scale0; }
    else if (blockIdx.z == 1) { W = W1; bias = bias1; C = C1; scale = 1.f; }
    else                      { W = W2; bias = bias2; C = C2; scale = 1.f; }

    const int tid  = threadIdx.x;
    const int wave = tid >> 6;
    const int lane = tid & 63;
    const int quad = lane >> 4;
    const int l16  = lane & 15;
    const int wm   = wave & 1;
    const int wn   = wave >> 1;
    const int m0   = blockIdx.y * 128;
    const int n0   = blockIdx.x * 128;

    __shared__ short As[128 * 32];
    __shared__ short Bs[128 * 32];

    const int srow = tid >> 2;
    const int skq  = tid & 3;
    const short* Ag = A + (size_t)(m0 + srow) * Kd + skq * 8;
    const short* Wg = W + (size_t)(n0 + srow) * Kd + skq * 8;
    short* AsP = As + srow * 32 + skq * 8;
    short* BsP = Bs + srow * 32 + skq * 8;

    f32x4 acc[4][4] = {};

    for (int kt = 0; kt < Kd; kt += 32) {
        __syncthreads();
        gld16(Ag + kt,                AsP);
        gld16(Ag + kt + 64 * Kd,      AsP + 64 * 32);
        gld16(Wg + kt,                BsP);
        gld16(Wg + kt + 64 * Kd,      BsP + 64 * 32);
        __syncthreads();

        bf16x8 af[4], bfr[4];
#pragma unroll
        for (int mt = 0; mt < 4; ++mt)
            af[mt] = *(const bf16x8*)&As[(wm * 64 + mt * 16 + l16) * 32 + quad * 8];
#pragma unroll
        for (int nt = 0; nt < 4; ++nt)
            bfr[nt] = *(const bf16x8*)&Bs[(wn * 64 + nt * 16 + l16) * 32 + quad * 8];
#pragma unroll
        for (int mt = 0; mt < 4; ++mt)
#pragma unroll
            for (int nt = 0; nt < 4; ++nt)
                acc[mt][nt] = __builtin_amdgcn_mfma_f32_16x16x32_bf16(
                    af[mt], bfr[nt], acc[mt][nt], 0, 0, 0);
    }

    float bv[4];
#pragma unroll
    for (int nt = 0; nt < 4; ++nt) bv[nt] = bias[n0 + wn * 64 + nt * 16 + l16];

#pragma unroll
    for (int mt = 0; mt < 4; ++mt)
#pragma unroll
        for (int nt = 0; nt < 4; ++nt)
#pragma unroll
            for (int reg = 0; reg < 4; ++reg) {
                const int m = m0 + wm * 64 + mt * 16 + quad * 4 + reg;
                const int n = n0 + wn * 64 + nt * 16 + l16;
                const float v = (acc[mt][nt][reg] + bv[nt]) * scale;
                if (BF16OUT) ((short*)C)[(size_t)m * N + n] = f2bf(v);
                else         ((float*)C)[(size_t)m * N + n] = v;
            }
}

// ---------------------------------------------------------------------------
// V pre-transpose: V[b,s,h*64+d] -> Vtg[((b*NH+h)*64+d)*SEQ + tile*64 + s']
// with in-tile permutation s' = 4*(key%16) + key/16 (matches attention's
// packed-P key order). Proven correct in round 6.
// ---------------------------------------------------------------------------
__global__ __launch_bounds__(256) void vtrans_kernel(
    const short* __restrict__ Vb, short* __restrict__ Vtg) {
    const int b  = blockIdx.z;
    const int h  = blockIdx.y;
    const int k0 = blockIdx.x * 64;
    const int kl = threadIdx.x & 15;
    const int d0 = (threadIdx.x >> 4) * 4;   // 0..60

    s16x4 vr[4];
#pragma unroll
    for (int g = 0; g < 4; ++g)
        vr[g] = *(const s16x4*)(Vb + (size_t)(b * SEQ + k0 + g * 16 + kl) * DIM
                                + h * HDIM + d0);
#pragma unroll
    for (int i = 0; i < 4; ++i) {
        s16x4 w = {vr[0][i], vr[1][i], vr[2][i], vr[3][i]};
        *(s16x4*)(Vtg + (size_t)((b * NH + h) * HDIM + d0 + i) * SEQ + k0 + 4 * kl) = w;
    }
}

// ---------------------------------------------------------------------------
// MFMA flash attention v5 — BARRIER-FREE.
// Waves are fully independent: wave handles 32 q rows (2 row groups).
// K fragments loaded DIRECTLY from global Kb (per (g,ks): 16 rows x aligned
// 64B — clean sectors, L2-resident). V fragments loaded directly from the
// pre-transposed Vtg (same pattern). Only P touches LDS: wave-private 4 KB,
// XOR-swizzled 8-short chunks (pos = chunk ^ (row&7)) -> conflict-free b128
// reads. No __syncthreads anywhere in the K loop. No-max exp2 softmax
// (0.125*log2e folded into Q); mask applied post-pack by bitwise AND;
// l accumulated via ones-MFMA.
// ---------------------------------------------------------------------------
__global__ __launch_bounds__(256, 3) void attn_mfma5(
    const short* __restrict__ Qb, const short* __restrict__ Kb,
    const short* __restrict__ Vtg, const void* __restrict__ ctxp,
    const int* __restrict__ flagp, short* __restrict__ Ob) {
    const int b    = blockIdx.z;
    const int h    = blockIdx.y;
    const int tid  = threadIdx.x;
    const int wave = tid >> 6;
    const int lane = tid & 63;
    const int quad = lane >> 4;
    const int l16  = lane & 15;
    const int qbase = blockIdx.x * 128 + wave * 32;
    const bool isU8 = (*flagp != 0);

    __shared__ short Ps[4][32 * 64];   // per-wave P, swizzled; 4 KB each
    short* Pw = Ps[wave];

    // Q fragments: rows qbase + rg*16 + l16.
    bf16x8 qf[2][2];
#pragma unroll
    for (int rg = 0; rg < 2; ++rg) {
        const short* qp = Qb + (size_t)(b * SEQ + qbase + rg * 16 + l16) * DIM
                        + h * HDIM + quad * 8;
        qf[rg][0] = *(const bf16x8*)qp;
        qf[rg][1] = *(const bf16x8*)(qp + 32);
    }

    // ~qctx per (rg, C-row): 0 for context rows, ~0 for target rows.
    unsigned nmb[2][4];
#pragma unroll
    for (int rg = 0; rg < 2; ++rg)
#pragma unroll
        for (int reg = 0; reg < 4; ++reg)
            nmb[rg][reg] = ctx_at(ctxp, isU8,
                b * SEQ + qbase + rg * 16 + quad * 4 + reg) ? 0u : 0xFFFFFFFFu;

    bf16x8 ones;
#pragma unroll
    for (int i = 0; i < 8; ++i) ones[i] = (short)0x3F80;  // bf16 1.0

    f32x4 accl[2] = {};
    f32x4 acc[2][4] = {};

    const short* Kg = Kb + (size_t)b * SEQ * DIM + h * HDIM;
    const short* Vg = Vtg + (size_t)(b * NH + h) * HDIM * SEQ;
    const int swl = l16 & 7;             // read-swizzle component
    const int pwb = (l16 >> 1);          // write chunk

    for (int t = 0; t < SEQ / 64; ++t) {
        const int k0 = t * 64;

        // Key-keep masks (1-byte ctx load + ballot).
        const unsigned long long kmask =
            __ballot(ctx_at(ctxp, isU8, b * SEQ + k0 + lane));
        unsigned km2[2];
#pragma unroll
        for (int gp = 0; gp < 2; ++gp) {
            const unsigned lo = (unsigned)((kmask >> (gp * 32 + l16)) & 1ull);
            const unsigned hi = (unsigned)((kmask >> (gp * 32 + 16 + l16)) & 1ull);
            km2[gp] = (lo ? 0x0000FFFFu : 0u) | (hi ? 0xFFFF0000u : 0u);
        }

        // V fragments (needed only at PV — latency covered by QK+softmax).
        bf16x8 vf[2][4];
#pragma unroll
        for (int ks = 0; ks < 2; ++ks)
#pragma unroll
            for (int dt = 0; dt < 4; ++dt)
                vf[ks][dt] = *(const bf16x8*)(Vg + (size_t)(dt * 16 + l16) * SEQ
                                              + k0 + ks * 32 + quad * 8);

        // S = Q @ K^T with K fragments straight from global.
        f32x4 s4[2][4] = {};
#pragma unroll
        for (int ks = 0; ks < 2; ++ks) {
            bf16x8 kf[4];
#pragma unroll
            for (int g = 0; g < 4; ++g)
                kf[g] = *(const bf16x8*)(Kg + (size_t)(k0 + g * 16 + l16) * DIM
                                         + ks * 32 + quad * 8);
#pragma unroll
            for (int g = 0; g < 4; ++g) {
                s4[0][g] = __builtin_amdgcn_mfma_f32_16x16x32_bf16(qf[0][ks], kf[g], s4[0][g], 0, 0, 0);
                s4[1][g] = __builtin_amdgcn_mfma_f32_16x16x32_bf16(qf[1][ks], kf[g], s4[1][g], 0, 0, 0);
            }
        }

        // p = exp2(s); pack; mask by AND; write P swizzled (key s = 4*l16+g).
#pragma unroll
        for (int rg = 0; rg < 2; ++rg)
#pragma unroll
            for (int reg = 0; reg < 4; ++reg) {
                const float p0 = fast_exp2(s4[rg][0][reg]);
                const float p1 = fast_exp2(s4[rg][1][reg]);
                const float p2 = fast_exp2(s4[rg][2][reg]);
                const float p3 = fast_exp2(s4[rg][3][reg]);
                uint2 w;
                w.x = pack_bf16x2(p0, p1) & (nmb[rg][reg] | km2[0]);
                w.y = pack_bf16x2(p2, p3) & (nmb[rg][reg] | km2[1]);
                const int row = rg * 16 + quad * 4 + reg;
                const int pos = pwb ^ (row & 7);
                *(uint2*)&Pw[row * 64 + pos * 8 + (l16 & 1) * 4] = w;
            }

        // O += P @ V ; l += P @ 1. P read conflict-free via swizzle.
#pragma unroll
        for (int ks = 0; ks < 2; ++ks) {
            const int rpos = (ks * 4 + quad) ^ swl;
            bf16x8 pf0 = *(const bf16x8*)&Pw[l16 * 64 + rpos * 8];
            bf16x8 pf1 = *(const bf16x8*)&Pw[(16 + l16) * 64 + rpos * 8];
            accl[0] = __builtin_amdgcn_mfma_f32_16x16x32_bf16(pf0, ones, accl[0], 0, 0, 0);
            accl[1] = __builtin_amdgcn_mfma_f32_16x16x32_bf16(pf1, ones, accl[1], 0, 0, 0);
#pragma unroll
            for (int dt = 0; dt < 4; ++dt) {
                acc[0][dt] = __builtin_amdgcn_mfma_f32_16x16x32_bf16(pf0, vf[ks][dt], acc[0][dt], 0, 0, 0);
                acc[1][dt] = __builtin_amdgcn_mfma_f32_16x16x32_bf16(pf1, vf[ks][dt], acc[1][dt], 0, 0, 0);
            }
        }
    }

    float inv[2][4];
#pragma unroll
    for (int rg = 0; rg < 2; ++rg)
#pragma unroll
        for (int reg = 0; reg < 4; ++reg)
            inv[rg][reg] = 1.f / accl[rg][reg];

#pragma unroll
    for (int rg = 0; rg < 2; ++rg)
#pragma unroll
        for (int dt = 0; dt < 4; ++dt)
#pragma unroll
            for (int reg = 0; reg < 4; ++reg) {
                const int q = qbase + rg * 16 + quad * 4 + reg;
                Ob[(size_t)(b * SEQ + q) * DIM + h * HDIM + dt * 16 + l16] =
                    f2bf(acc[rg][dt][reg] * inv[rg][reg]);
            }
}

// ---------------------------------------------------------------------------
// kernel_launch
// ---------------------------------------------------------------------------
extern "C" void kernel_launch(void* const* d_in, const int* in_sizes, int n_in,
                              void* d_out, int out_size, void* d_ws, size_t ws_size,
                              hipStream_t stream) {
    const float* x   = (const float*)d_in[0];
    const void*  ctx = d_in[1];
    const float* Wq  = (const float*)d_in[2];
    const float* bq  = (const float*)d_in[3];
    const float* Wk  = (const float*)d_in[4];
    const float* bk  = (const float*)d_in[5];
    const float* Wv  = (const float*)d_in[6];
    const float* bv  = (const float*)d_in[7];
    const float* Wo  = (const float*)d_in[8];
    const float* bo  = (const float*)d_in[9];
    float* out = (float*)d_out;

    char* ws = (char*)d_ws;
    int* flag = (int*)ws;
    const size_t bufbf = (size_t)BATCH * SEQ * DIM * sizeof(short);  // 12.6 MB
    const size_t wbuf  = (size_t)DIM * DIM * sizeof(short);          // 1.18 MB
    short* xb  = (short*)(ws + 256);
    short* Qb  = (short*)(ws + 256 + bufbf);
    short* Kb  = (short*)(ws + 256 + 2 * bufbf);
    short* Vb  = (short*)(ws + 256 + 3 * bufbf);
    short* Ab  = (short*)(ws + 256 + 4 * bufbf);
    short* Vtg = (short*)(ws + 256 + 5 * bufbf);
    short* Wqb = (short*)(ws + 256 + 6 * bufbf);
    short* Wkb = (short*)(ws + 256 + 6 * bufbf + wbuf);
    short* Wvb = (short*)(ws + 256 + 6 * bufbf + 2 * wbuf);
    short* Wob = (short*)(ws + 256 + 6 * bufbf + 3 * wbuf);

    constexpr int XBLK = (BATCH * SEQ * DIM / 4) / 256;  // 6144
    constexpr int WBLK = (DIM * DIM / 4) / 256;          // 576
    prep_kernel<<<XBLK + 4 * WBLK + 1, 256, 0, stream>>>(
        x, Wq, Wk, Wv, Wo, xb, Wqb, Wkb, Wvb, Wob,
        (const unsigned char*)ctx, BATCH * SEQ, flag);

    // Q scale = 0.125 * log2(e): scores arrive in exp2 domain.
    dim3 gQKV(DIM / 128, (BATCH * SEQ) / 128, 3);
    gemm_mfma<true><<<gQKV, 256, 0, stream>>>(
        xb, Wqb, bq, Qb, Wkb, bk, Kb, Wvb, bv, Vb, 0.125f * 1.4426950408889634f);

    dim3 gVt(SEQ / 64, NH, BATCH);
    vtrans_kernel<<<gVt, 256, 0, stream>>>(Vb, Vtg);

    dim3 gAttn(SEQ / 128, NH, BATCH);
    attn_mfma5<<<gAttn, 256, 0, stream>>>(Qb, Kb, Vtg, ctx, flag, Ab);

    dim3 gOut(DIM / 128, (BATCH * SEQ) / 128, 1);
    gemm_mfma<false><<<gOut, 256, 0, stream>>>(
        Ab, Wob, bo, out, Wob, bo, out, Wob, bo, out, 1.f);
}

// Round 8
// 254.274 us; speedup vs baseline: 1.4483x; 1.4074x over previous
//
#include <hip/hip_runtime.h>
#include <hip/hip_bf16.h>

constexpr int BATCH = 4;
constexpr int SEQ   = 2048;
constexpr int DIM   = 768;
constexpr int NH    = 12;
constexpr int HDIM  = 64;

typedef __attribute__((ext_vector_type(8))) short bf16x8;
typedef __attribute__((ext_vector_type(4))) float f32x4;
typedef __attribute__((ext_vector_type(4))) short s16x4;

__device__ inline short f2bf(float f) {
    union { float f; unsigned u; } v; v.f = f;
    unsigned r = (v.u + 0x7fff + ((v.u >> 16) & 1)) >> 16;  // RNE
    return (short)r;
}

__device__ inline unsigned pack_bf16x2(float a, float b) {
    union { __hip_bfloat162 h; unsigned u; } c;
    c.h = __float22bfloat162_rn(make_float2(a, b));
    return c.u;
}

__device__ inline float fast_exp2(float x) {
#if __has_builtin(__builtin_amdgcn_exp2f)
    return __builtin_amdgcn_exp2f(x);
#else
    return __expf(x * 0.6931471805599453f);
#endif
}

__device__ inline void gld16(const short* g, short* l) {
    __builtin_amdgcn_global_load_lds(
        (const __attribute__((address_space(1))) void*)g,
        (__attribute__((address_space(3))) void*)l, 16, 0, 0);
}

__device__ inline bool ctx_at(const void* p, bool isU8, int idx) {
    return isU8 ? (((const unsigned char*)p)[idx] != 0)
                : (((const int*)p)[idx] != 0);
}

// ---------------------------------------------------------------------------
// prep: fused fp32->bf16 casts (x, Wq, Wk, Wv, Wo) + mask-layout detect.
// ---------------------------------------------------------------------------
__global__ __launch_bounds__(256) void prep_kernel(
    const float* __restrict__ x,  const float* __restrict__ Wq,
    const float* __restrict__ Wk, const float* __restrict__ Wv,
    const float* __restrict__ Wo,
    short* __restrict__ xb,  short* __restrict__ Wqb,
    short* __restrict__ Wkb, short* __restrict__ Wvb,
    short* __restrict__ Wob,
    const unsigned char* __restrict__ ctxm, int ctxbytes, int* __restrict__ flag) {
    const int blk = blockIdx.x;
    constexpr int XBLK = (BATCH * SEQ * DIM / 4) / 256;  // 6144
    constexpr int WBLK = (DIM * DIM / 4) / 256;          // 576

    if (blk == XBLK + 4 * WBLK) {
        __shared__ int cnt;
        if (threadIdx.x == 0) cnt = 0;
        __syncthreads();
        int local = 0;
        for (int i = threadIdx.x; i < ctxbytes; i += 256)
            if ((i & 3) != 0 && ctxm[i] != 0) local++;
        atomicAdd(&cnt, local);
        __syncthreads();
        if (threadIdx.x == 0) *flag = (cnt > 0) ? 1 : 0;
        return;
    }

    const float* src; short* dst; int i;
    if (blk < XBLK) {
        src = x; dst = xb;
        i = blk * 256 + threadIdx.x;
    } else {
        const int r = blk - XBLK;
        const int w = r / WBLK;
        src = (w == 0) ? Wq : (w == 1) ? Wk : (w == 2) ? Wv : Wo;
        dst = (w == 0) ? Wqb : (w == 1) ? Wkb : (w == 2) ? Wvb : Wob;
        i = (r - w * WBLK) * 256 + threadIdx.x;
    }
    float4 v = ((const float4*)src)[i];
    s16x4 o;
    o.x = f2bf(v.x); o.y = f2bf(v.y); o.z = f2bf(v.z); o.w = f2bf(v.w);
    ((s16x4*)dst)[i] = o;
}

// ---------------------------------------------------------------------------
// m97-style MFMA GEMM (unchanged).
// ---------------------------------------------------------------------------
template <bool BF16OUT>
__global__ __launch_bounds__(256) void gemm_mfma(
    const short* __restrict__ A,
    const short* __restrict__ W0, const float* __restrict__ bias0, void* __restrict__ C0,
    const short* __restrict__ W1, const float* __restrict__ bias1, void* __restrict__ C1,
    const short* __restrict__ W2, const float* __restrict__ bias2, void* __restrict__ C2,
    float scale0) {
    constexpr int N  = DIM;
    constexpr int Kd = DIM;

    const short* W; const float* bias; void* C; float scale;
    if (blockIdx.z == 0)      { W = W0; bias = bias0; C = C0; scale = scale0; }
    else if (blockIdx.z == 1) { W = W1; bias = bias1; C = C1; scale = 1.f; }
    else                      { W = W2; bias = bias2; C = C2; scale = 1.f; }

    const int tid  = threadIdx.x;
    const int wave = tid >> 6;
    const int lane = tid & 63;
    const int quad = lane >> 4;
    const int l16  = lane & 15;
    const int wm   = wave & 1;
    const int wn   = wave >> 1;
    const int m0   = blockIdx.y * 128;
    const int n0   = blockIdx.x * 128;

    __shared__ short As[128 * 32];
    __shared__ short Bs[128 * 32];

    const int srow = tid >> 2;
    const int skq  = tid & 3;
    const short* Ag = A + (size_t)(m0 + srow) * Kd + skq * 8;
    const short* Wg = W + (size_t)(n0 + srow) * Kd + skq * 8;
    short* AsP = As + srow * 32 + skq * 8;
    short* BsP = Bs + srow * 32 + skq * 8;

    f32x4 acc[4][4] = {};

    for (int kt = 0; kt < Kd; kt += 32) {
        __syncthreads();
        gld16(Ag + kt,                AsP);
        gld16(Ag + kt + 64 * Kd,      AsP + 64 * 32);
        gld16(Wg + kt,                BsP);
        gld16(Wg + kt + 64 * Kd,      BsP + 64 * 32);
        __syncthreads();

        bf16x8 af[4], bfr[4];
#pragma unroll
        for (int mt = 0; mt < 4; ++mt)
            af[mt] = *(const bf16x8*)&As[(wm * 64 + mt * 16 + l16) * 32 + quad * 8];
#pragma unroll
        for (int nt = 0; nt < 4; ++nt)
            bfr[nt] = *(const bf16x8*)&Bs[(wn * 64 + nt * 16 + l16) * 32 + quad * 8];
#pragma unroll
        for (int mt = 0; mt < 4; ++mt)
#pragma unroll
            for (int nt = 0; nt < 4; ++nt)
                acc[mt][nt] = __builtin_amdgcn_mfma_f32_16x16x32_bf16(
                    af[mt], bfr[nt], acc[mt][nt], 0, 0, 0);
    }

    float bv[4];
#pragma unroll
    for (int nt = 0; nt < 4; ++nt) bv[nt] = bias[n0 + wn * 64 + nt * 16 + l16];

#pragma unroll
    for (int mt = 0; mt < 4; ++mt)
#pragma unroll
        for (int nt = 0; nt < 4; ++nt)
#pragma unroll
            for (int reg = 0; reg < 4; ++reg) {
                const int m = m0 + wm * 64 + mt * 16 + quad * 4 + reg;
                const int n = n0 + wn * 64 + nt * 16 + l16;
                const float v = (acc[mt][nt][reg] + bv[nt]) * scale;
                if (BF16OUT) ((short*)C)[(size_t)m * N + n] = f2bf(v);
                else         ((float*)C)[(size_t)m * N + n] = v;
            }
}

// ---------------------------------------------------------------------------
// V pre-transpose: V[b,s,h*64+d] -> Vtg[((b*NH+h)*64+d)*SEQ + tile*64 + s']
// with in-tile permutation s' = 4*(key%16) + key/16 (matches attention's
// packed-P key order). Proven correct rounds 6-7.
// ---------------------------------------------------------------------------
__global__ __launch_bounds__(256) void vtrans_kernel(
    const short* __restrict__ Vb, short* __restrict__ Vtg) {
    const int b  = blockIdx.z;
    const int h  = blockIdx.y;
    const int k0 = blockIdx.x * 64;
    const int kl = threadIdx.x & 15;
    const int d0 = (threadIdx.x >> 4) * 4;   // 0..60

    s16x4 vr[4];
#pragma unroll
    for (int g = 0; g < 4; ++g)
        vr[g] = *(const s16x4*)(Vb + (size_t)(b * SEQ + k0 + g * 16 + kl) * DIM
                                + h * HDIM + d0);
#pragma unroll
    for (int i = 0; i < 4; ++i) {
        s16x4 w = {vr[0][i], vr[1][i], vr[2][i], vr[3][i]};
        *(s16x4*)(Vtg + (size_t)((b * NH + h) * HDIM + d0 + i) * SEQ + k0 + 4 * kl) = w;
    }
}

// ---------------------------------------------------------------------------
// MFMA flash attention v6 = r4 structure + async double-buffered staging +
// full XOR-swizzled LDS (zero bank conflicts, proven r7) + proven VALU cuts.
//
// Block = (b, h, 128 q rows); 4 waves x 32 q rows. One barrier per key tile:
//   barrier -> issue gld16 of tile t+1 into buf^1 -> compute tile t.
// The compiler's vmcnt(0)-before-barrier then lands AFTER a full tile of
// compute, hiding global latency with zero prefetch VGPRs (r6's spill bug
// is structurally impossible).
//
// Swizzled LDS layout (16B chunks): chunk_addr(row, j) = row*8 + (j^(row&7)).
// Staging realizes it with j0 = (tid&7)^((tid>>3)&7): issue covers rows
// tid>>3 (+32), 8x128B contiguous rows per wave -> clean coalescing.
// ---------------------------------------------------------------------------
__global__ __launch_bounds__(256, 3) void attn_mfma6(
    const short* __restrict__ Qb, const short* __restrict__ Kb,
    const short* __restrict__ Vtg, const void* __restrict__ ctxp,
    const int* __restrict__ flagp, short* __restrict__ Ob) {
    const int b    = blockIdx.z;
    const int h    = blockIdx.y;
    const int q0   = blockIdx.x * 128;
    const int tid  = threadIdx.x;
    const int wave = tid >> 6;
    const int lane = tid & 63;
    const int quad = lane >> 4;
    const int l16  = lane & 15;
    const bool isU8 = (*flagp != 0);

    __shared__ short Ks[2][64 * 64];   // 8 KB x2, swizzled chunks
    __shared__ short Vs[2][64 * 64];   // 8 KB x2, swizzled chunks (s-permuted)
    __shared__ short Ps[4][32 * 64];   // per-wave P, swizzled; 4 KB each

    short* Pw = Ps[wave];

    const short* Kg = Kb + (size_t)b * SEQ * DIM + h * HDIM;
    const short* Vg = Vtg + (size_t)(b * NH + h) * HDIM * SEQ;

    // Staging map: thread covers rows r0 and r0+32, d/s-chunk j0 (swizzle).
    const int r0 = tid >> 3;
    const int j0 = (tid & 7) ^ (r0 & 7);
    const int sw = l16 & 7;            // fragment-read swizzle component

    // Q fragments: rows q0 + wave*32 + rg*16 + l16.
    bf16x8 qf[2][2];
#pragma unroll
    for (int rg = 0; rg < 2; ++rg) {
        const short* qp = Qb + (size_t)(b * SEQ + q0 + wave * 32 + rg * 16 + l16) * DIM
                        + h * HDIM + quad * 8;
        qf[rg][0] = *(const bf16x8*)qp;
        qf[rg][1] = *(const bf16x8*)(qp + 32);
    }

    // ~qctx per (rg, C-row): 0 for context rows, ~0 for target rows.
    unsigned nmb[2][4];
#pragma unroll
    for (int rg = 0; rg < 2; ++rg)
#pragma unroll
        for (int reg = 0; reg < 4; ++reg)
            nmb[rg][reg] = ctx_at(ctxp, isU8,
                b * SEQ + q0 + wave * 32 + rg * 16 + quad * 4 + reg) ? 0u : 0xFFFFFFFFu;

    bf16x8 ones;
#pragma unroll
    for (int i = 0; i < 8; ++i) ones[i] = (short)0x3F80;  // bf16 1.0

    f32x4 accl[2] = {};
    f32x4 acc[2][4] = {};

    // Prologue: stage tile 0 into buffer 0.
    {
        gld16(Kg + (size_t)r0 * DIM + j0 * 8,        &Ks[0][tid * 8]);
        gld16(Kg + (size_t)(r0 + 32) * DIM + j0 * 8, &Ks[0][(tid + 256) * 8]);
        gld16(Vg + (size_t)r0 * SEQ + j0 * 8,        &Vs[0][tid * 8]);
        gld16(Vg + (size_t)(r0 + 32) * SEQ + j0 * 8, &Vs[0][(tid + 256) * 8]);
    }

    constexpr int NT = SEQ / 64;
    for (int t = 0; t < NT; ++t) {
        const int k0  = t * 64;
        const int cur = t & 1;

        __syncthreads();   // own vmcnt(0) drains before barrier -> buf[cur] ready

        // Issue next tile's async loads into the other buffer (no VGPRs held).
        if (t + 1 < NT) {
            const int kn  = k0 + 64;
            const int nxt = cur ^ 1;
            gld16(Kg + (size_t)(kn + r0) * DIM + j0 * 8,        &Ks[nxt][tid * 8]);
            gld16(Kg + (size_t)(kn + r0 + 32) * DIM + j0 * 8,   &Ks[nxt][(tid + 256) * 8]);
            gld16(Vg + (size_t)r0 * SEQ + kn + j0 * 8,          &Vs[nxt][tid * 8]);
            gld16(Vg + (size_t)(r0 + 32) * SEQ + kn + j0 * 8,   &Vs[nxt][(tid + 256) * 8]);
        }

        const short* BK = Ks[cur];
        const short* BV = Vs[cur];

        // Key-keep masks for this tile.
        const unsigned long long kmask =
            __ballot(ctx_at(ctxp, isU8, b * SEQ + k0 + lane));
        unsigned km2[2];
#pragma unroll
        for (int gp = 0; gp < 2; ++gp) {
            const unsigned lo = (unsigned)((kmask >> (gp * 32 + l16)) & 1ull);
            const unsigned hi = (unsigned)((kmask >> (gp * 32 + 16 + l16)) & 1ull);
            km2[gp] = (lo ? 0x0000FFFFu : 0u) | (hi ? 0xFFFF0000u : 0u);
        }

        // S = Q @ K^T (log2 domain; 0.125*log2e folded into Q).
        f32x4 s4[2][4] = {};
#pragma unroll
        for (int ks = 0; ks < 2; ++ks) {
            bf16x8 kf[4];
#pragma unroll
            for (int g = 0; g < 4; ++g)
                kf[g] = *(const bf16x8*)
                    &BK[(g * 16 + l16) * 64 + (((ks * 4 + quad) ^ sw)) * 8];
#pragma unroll
            for (int g = 0; g < 4; ++g) {
                s4[0][g] = __builtin_amdgcn_mfma_f32_16x16x32_bf16(qf[0][ks], kf[g], s4[0][g], 0, 0, 0);
                s4[1][g] = __builtin_amdgcn_mfma_f32_16x16x32_bf16(qf[1][ks], kf[g], s4[1][g], 0, 0, 0);
            }
        }

        // p = exp2(s); pack; mask post-pack by AND; write P swizzled.
#pragma unroll
        for (int rg = 0; rg < 2; ++rg)
#pragma unroll
            for (int reg = 0; reg < 4; ++reg) {
                const float p0 = fast_exp2(s4[rg][0][reg]);
                const float p1 = fast_exp2(s4[rg][1][reg]);
                const float p2 = fast_exp2(s4[rg][2][reg]);
                const float p3 = fast_exp2(s4[rg][3][reg]);
                uint2 w;
                w.x = pack_bf16x2(p0, p1) & (nmb[rg][reg] | km2[0]);
                w.y = pack_bf16x2(p2, p3) & (nmb[rg][reg] | km2[1]);
                const int row = rg * 16 + quad * 4 + reg;
                const int pos = (l16 >> 1) ^ (row & 7);
                *(uint2*)&Pw[row * 64 + pos * 8 + (l16 & 1) * 4] = w;
            }

        // O += P @ V ; l += P @ 1  (all LDS reads conflict-free).
#pragma unroll
        for (int ks = 0; ks < 2; ++ks) {
            const int rpos = (ks * 4 + quad) ^ sw;
            bf16x8 pf0 = *(const bf16x8*)&Pw[l16 * 64 + rpos * 8];
            bf16x8 pf1 = *(const bf16x8*)&Pw[(16 + l16) * 64 + rpos * 8];
            accl[0] = __builtin_amdgcn_mfma_f32_16x16x32_bf16(pf0, ones, accl[0], 0, 0, 0);
            accl[1] = __builtin_amdgcn_mfma_f32_16x16x32_bf16(pf1, ones, accl[1], 0, 0, 0);
#pragma unroll
            for (int dt = 0; dt < 4; ++dt) {
                bf16x8 vf = *(const bf16x8*)
                    &BV[(dt * 16 + l16) * 64 + (((ks * 4 + quad) ^ sw)) * 8];
                acc[0][dt] = __builtin_amdgcn_mfma_f32_16x16x32_bf16(pf0, vf, acc[0][dt], 0, 0, 0);
                acc[1][dt] = __builtin_amdgcn_mfma_f32_16x16x32_bf16(pf1, vf, acc[1][dt], 0, 0, 0);
            }
        }
    }

    float inv[2][4];
#pragma unroll
    for (int rg = 0; rg < 2; ++rg)
#pragma unroll
        for (int reg = 0; reg < 4; ++reg)
            inv[rg][reg] = 1.f / accl[rg][reg];

#pragma unroll
    for (int rg = 0; rg < 2; ++rg)
#pragma unroll
        for (int dt = 0; dt < 4; ++dt)
#pragma unroll
            for (int reg = 0; reg < 4; ++reg) {
                const int q = q0 + wave * 32 + rg * 16 + quad * 4 + reg;
                Ob[(size_t)(b * SEQ + q) * DIM + h * HDIM + dt * 16 + l16] =
                    f2bf(acc[rg][dt][reg] * inv[rg][reg]);
            }
}

// ---------------------------------------------------------------------------
// kernel_launch
// ---------------------------------------------------------------------------
extern "C" void kernel_launch(void* const* d_in, const int* in_sizes, int n_in,
                              void* d_out, int out_size, void* d_ws, size_t ws_size,
                              hipStream_t stream) {
    const float* x   = (const float*)d_in[0];
    const void*  ctx = d_in[1];
    const float* Wq  = (const float*)d_in[2];
    const float* bq  = (const float*)d_in[3];
    const float* Wk  = (const float*)d_in[4];
    const float* bk  = (const float*)d_in[5];
    const float* Wv  = (const float*)d_in[6];
    const float* bv  = (const float*)d_in[7];
    const float* Wo  = (const float*)d_in[8];
    const float* bo  = (const float*)d_in[9];
    float* out = (float*)d_out;

    char* ws = (char*)d_ws;
    int* flag = (int*)ws;
    const size_t bufbf = (size_t)BATCH * SEQ * DIM * sizeof(short);  // 12.6 MB
    const size_t wbuf  = (size_t)DIM * DIM * sizeof(short);          // 1.18 MB
    short* xb  = (short*)(ws + 256);
    short* Qb  = (short*)(ws + 256 + bufbf);
    short* Kb  = (short*)(ws + 256 + 2 * bufbf);
    short* Vb  = (short*)(ws + 256 + 3 * bufbf);
    short* Ab  = (short*)(ws + 256 + 4 * bufbf);
    short* Vtg = (short*)(ws + 256 + 5 * bufbf);
    short* Wqb = (short*)(ws + 256 + 6 * bufbf);
    short* Wkb = (short*)(ws + 256 + 6 * bufbf + wbuf);
    short* Wvb = (short*)(ws + 256 + 6 * bufbf + 2 * wbuf);
    short* Wob = (short*)(ws + 256 + 6 * bufbf + 3 * wbuf);

    constexpr int XBLK = (BATCH * SEQ * DIM / 4) / 256;  // 6144
    constexpr int WBLK = (DIM * DIM / 4) / 256;          // 576
    prep_kernel<<<XBLK + 4 * WBLK + 1, 256, 0, stream>>>(
        x, Wq, Wk, Wv, Wo, xb, Wqb, Wkb, Wvb, Wob,
        (const unsigned char*)ctx, BATCH * SEQ, flag);

    // Q scale = 0.125 * log2(e): scores arrive in exp2 domain.
    dim3 gQKV(DIM / 128, (BATCH * SEQ) / 128, 3);
    gemm_mfma<true><<<gQKV, 256, 0, stream>>>(
        xb, Wqb, bq, Qb, Wkb, bk, Kb, Wvb, bv, Vb, 0.125f * 1.4426950408889634f);

    dim3 gVt(SEQ / 64, NH, BATCH);
    vtrans_kernel<<<gVt, 256, 0, stream>>>(Vb, Vtg);

    dim3 gAttn(SEQ / 128, NH, BATCH);
    attn_mfma6<<<gAttn, 256, 0, stream>>>(Qb, Kb, Vtg, ctx, flag, Ab);

    dim3 gOut(DIM / 128, (BATCH * SEQ) / 128, 1);
    gemm_mfma<false><<<gOut, 256, 0, stream>>>(
        Ab, Wob, bo, out, Wob, bo, out, Wob, bo, out, 1.f);
}